// Round 11
// baseline (59.776 us; speedup 1.0000x reference)
//
#include <hip/hip_runtime.h>

// Per-a batched GEMM, each H element fetched exactly once:
//   Yre[b,k] = sum_j Xre[b,j]*hr1[a,j,k] + Xim[b,j]*hi1[a,j,k]
//   Yim[b,k] = sum_j Xre[b,j]*hi2[a,j,k] + Xim[b,j]*hr2[a,j,k]
//
// Round-11: r10's per-wave structure (44 VGPR, spill-clean: WRITE=16 MB)
// inside a 512-thread block. Evidence: all 4-wave blocks pack ~3.2 WG/CU
// (occupancy stuck 35-42% across r2-r10 regardless of grid/VGPR/LDS);
// r8's 512-thread block reached 82% -> waves/CU scales with waves per WG,
// not WG count. r8 failed only via forced-VGPR spill (launch_bounds(512,8)
// -> 64-reg cap); here launch_bounds(512,2) keeps the cap at 128.
//   Block = one 'a', 512 threads = 8 waves: wave = (kh, ch, jh).
//   Lane = (m = lane>>5, bh = (lane>>4)&1, kg = lane&15):
//     k0 = kh*64 + kg*4; acc = 8 b x 4 k = 32 VGPR; ring-4 H prefetch.
//   H exactly-once per block; one shared x stage (r10 duplicated it).
// Epilogue: shfl-fold m halves; LDS-reduce jh halves per (kh,ch) tile.

__global__ __launch_bounds__(512, 2)
void hmat_kernel(const float* __restrict__ x,
                 const float* __restrict__ hr1,
                 const float* __restrict__ hi1,
                 const float* __restrict__ hr2,
                 const float* __restrict__ hi2,
                 const int* __restrict__ perm,
                 float* __restrict__ out) {
  __shared__ float lds[4096];  // x stage [j=128][col=c*16+b]; then reduce buf
  const int a = blockIdx.x;
  const int t = threadIdx.x;

  const int w    = t >> 6;          // wave 0..7
  const int kh   = w >> 2;          // k half
  const int ch   = (w >> 1) & 1;    // output channel
  const int jh   = w & 1;           // j half
  const int lane = t & 63;
  const int m    = lane >> 5;       // matrix of pair; x channel c == m
  const int bh   = (lane >> 4) & 1; // b half: 8 b each
  const int kg   = lane & 15;       // k group of 4 within this wave's 64 k
  const int k0   = kh * 64 + kg * 4;
  const int b0   = bh * 8;

  const float* __restrict__ Hm =
      (ch == 0) ? (m == 0 ? hr1 : hi1) : (m == 0 ? hi2 : hr2);
  const float* __restrict__ hp = Hm + (size_t)a * 16384 + k0;
  const int jofs = jh * 64;

  // ---- stage permuted x into LDS (r8's 512-thread 0-conflict pattern) ----
  {
    const int c   = t & 1;
    const int b   = (t >> 1) & 15;
    const int q   = t >> 5;
    const int jg  = q >> 2;
    const int seg = q & 3;
    const int row = perm[a * 4 + jg];
    const float4* src =
        (const float4*)(x + ((size_t)(b * 2 + c) * 4096 + (size_t)row) * 32 +
                        seg * 8);
    const float4 v0 = src[0];
    const float4 v1 = src[1];
    const int col = c * 16 + b;
    const int jb  = jg * 32 + seg * 8;
#define PUTX(V, Q)                            \
  lds[(jb + (Q)*4 + 0) * 32 + col] = (V).x;   \
  lds[(jb + (Q)*4 + 1) * 32 + col] = (V).y;   \
  lds[(jb + (Q)*4 + 2) * 32 + col] = (V).z;   \
  lds[(jb + (Q)*4 + 3) * 32 + col] = (V).w;
    PUTX(v0, 0) PUTX(v1, 1)
#undef PUTX
  }

  __syncthreads();

  // ring-4 H prefetch, immediate-consume (r3/r10 proven pattern)
  float4 pf0 = *(const float4*)(hp + (size_t)(jofs + 0) * 128);
  float4 pf1 = *(const float4*)(hp + (size_t)(jofs + 1) * 128);
  float4 pf2 = *(const float4*)(hp + (size_t)(jofs + 2) * 128);
  float4 pf3 = *(const float4*)(hp + (size_t)(jofs + 3) * 128);

  const float* __restrict__ xp = lds + m * 16 + b0;  // + J*32

  float4 acc[8];
#pragma unroll
  for (int i = 0; i < 8; ++i) acc[i] = make_float4(0.f, 0.f, 0.f, 0.f);

#define CONSUME(PF, J)                                                 \
  {                                                                    \
    const float4 xa = *(const float4*)(xp + (J) * 32);                 \
    const float4 xb = *(const float4*)(xp + (J) * 32 + 4);             \
    const float xs[8] = {xa.x, xa.y, xa.z, xa.w,                       \
                         xb.x, xb.y, xb.z, xb.w};                      \
    _Pragma("unroll") for (int bb = 0; bb < 8; ++bb) {                 \
      acc[bb].x = fmaf(xs[bb], (PF).x, acc[bb].x);                     \
      acc[bb].y = fmaf(xs[bb], (PF).y, acc[bb].y);                     \
      acc[bb].z = fmaf(xs[bb], (PF).z, acc[bb].z);                     \
      acc[bb].w = fmaf(xs[bb], (PF).w, acc[bb].w);                     \
    }                                                                  \
  }

  for (int j4 = 0; j4 < 60; j4 += 4) {
    CONSUME(pf0, jofs + j4 + 0)
    pf0 = *(const float4*)(hp + (size_t)(jofs + j4 + 4) * 128);
    CONSUME(pf1, jofs + j4 + 1)
    pf1 = *(const float4*)(hp + (size_t)(jofs + j4 + 5) * 128);
    CONSUME(pf2, jofs + j4 + 2)
    pf2 = *(const float4*)(hp + (size_t)(jofs + j4 + 6) * 128);
    CONSUME(pf3, jofs + j4 + 3)
    pf3 = *(const float4*)(hp + (size_t)(jofs + j4 + 7) * 128);
  }
  CONSUME(pf0, jofs + 60)
  CONSUME(pf1, jofs + 61)
  CONSUME(pf2, jofs + 62)
  CONSUME(pf3, jofs + 63)
#undef CONSUME

  // ---- fold the two matrix-halves: lane p += lane p^32 ----
#pragma unroll
  for (int bb = 0; bb < 8; ++bb) {
    acc[bb].x += __shfl_xor(acc[bb].x, 32, 64);
    acc[bb].y += __shfl_xor(acc[bb].y, 32, 64);
    acc[bb].z += __shfl_xor(acc[bb].z, 32, 64);
    acc[bb].w += __shfl_xor(acc[bb].w, 32, 64);
  }

  // ---- reduce the two j-halves via LDS (reuse x-stage region) ----
  // buf tile (kh*2+ch): 16 b x 64 k = 1024 floats; 4 tiles = 4096 ✓
  __syncthreads();  // all waves done reading the x stage
  const int tile = (kh * 2 + ch) * 1024;
  if (jh == 1 && m == 0) {
#pragma unroll
    for (int bb = 0; bb < 8; ++bb)
      *(float4*)&lds[tile + (b0 + bb) * 64 + kg * 4] = acc[bb];
  }
  __syncthreads();
  if (jh == 0 && m == 0) {
#pragma unroll
    for (int bb = 0; bb < 8; ++bb) {
      const float4 o = *(const float4*)&lds[tile + (b0 + bb) * 64 + kg * 4];
      const int b = b0 + bb;
      float4 r;
      r.x = acc[bb].x + o.x;
      r.y = acc[bb].y + o.y;
      r.z = acc[bb].z + o.z;
      r.w = acc[bb].w + o.w;
      *(float4*)(out + (size_t)(b * 2 + ch) * 131072 + (size_t)a * 128 + k0) =
          r;
    }
  }
}

extern "C" void kernel_launch(void* const* d_in, const int* in_sizes, int n_in,
                              void* d_out, int out_size, void* d_ws, size_t ws_size,
                              hipStream_t stream) {
  const float* x   = (const float*)d_in[0];
  const float* hr1 = (const float*)d_in[1];
  const float* hi1 = (const float*)d_in[2];
  const float* hr2 = (const float*)d_in[3];
  const float* hi2 = (const float*)d_in[4];
  const int* perm  = (const int*)d_in[5];
  float* out = (float*)d_out;

  hipLaunchKernelGGL(hmat_kernel, dim3(1024), dim3(512), 0, stream,
                     x, hr1, hi1, hr2, hi2, perm, out);
}